// Round 14
// baseline (55.815 us; speedup 1.0000x reference)
//
#include <hip/hip_runtime.h>

#define L 512
#define D 768
#define LL (L * L)
#define LOG2E  1.44269504088896341f
#define LOG2E2 2.88539008177792681f   // 2*log2(e)
#define DH 16                          // d-split factor
#define DSEG (D / DH)                  // 48
#define QB 8                           // q-rows per block in score_k

typedef __attribute__((ext_vector_type(8))) short bf16x8;
typedef __attribute__((ext_vector_type(4))) float f32x4;

__device__ __forceinline__ ushort f2bf(float f) {
    unsigned u = __builtin_bit_cast(unsigned, f);
    u += 0x7FFFu + ((u >> 16) & 1u);          // RNE
    return (ushort)(u >> 16);
}

// ---------------- prep: cast X->bf16; transposed bf16 copies of Wq/Wk/Wt ------
// z: 0 = X cast only (512x768), 1 = Wq^T, 2 = Wk^T, 3 = Wt^T (768x768)
__global__ __launch_bounds__(256) void transpose_cast(
    const float* __restrict__ X,  const float* __restrict__ Wq,
    const float* __restrict__ Wk, const float* __restrict__ Wt,
    ushort* __restrict__ Xbf,
    ushort* __restrict__ WqT, ushort* __restrict__ WkT, ushort* __restrict__ WtT)
{
    __shared__ float tile[64][65];
    const int z = blockIdx.z;
    const float* src = z == 0 ? X : z == 1 ? Wq : z == 2 ? Wk : Wt;
    ushort* dstT     = z == 1 ? WqT : z == 2 ? WkT : WtT;
    const int R = (z == 0) ? L : D;
    const int r0 = blockIdx.y * 64, c0 = blockIdx.x * 64;
    if (r0 >= R) return;
    const int t = threadIdx.x;
    const int tr = t >> 4;           // 0..15
    const int tc = (t & 15) * 4;     // 0..60
    #pragma unroll
    for (int p = 0; p < 4; ++p) {
        int r = tr + p * 16;
        float4 v = *(const float4*)&src[(r0 + r) * D + c0 + tc];
        tile[r][tc + 0] = v.x; tile[r][tc + 1] = v.y;
        tile[r][tc + 2] = v.z; tile[r][tc + 3] = v.w;
        if (z == 0) {
            ushort4 b;
            b.x = f2bf(v.x); b.y = f2bf(v.y); b.z = f2bf(v.z); b.w = f2bf(v.w);
            *(ushort4*)&Xbf[(r0 + r) * D + c0 + tc] = b;
        }
    }
    if (z == 0) return;
    __syncthreads();
    #pragma unroll
    for (int p = 0; p < 4; ++p) {
        int c = tr + p * 16;
        ushort4 b;
        b.x = f2bf(tile[tc + 0][c]);
        b.y = f2bf(tile[tc + 1][c]);
        b.z = f2bf(tile[tc + 2][c]);
        b.w = f2bf(tile[tc + 3][c]);
        *(ushort4*)&dstT[(c0 + c) * R + r0 + tc] = b;
    }
}

// ---------------- bf16 MFMA GEMM, 32x64 tile, BK=64, 4 waves ------------------
// MODE 0 (z in {0,1,2}, K=768, A=Xbf):
//   z=0: Qb = acc + bq (fp32) AND Eq = exp2(c*(acc+bq)) (fp32), both row-major
//   z=1: EkT[col][row0..3] = exp2(c*(acc + bk))   (transposed float4 store)
//   z=2: XWtT[col][row0..3] = bf16(acc)           (transposed ushort4 store)
// MODE 1 (K=512, A=Pbf, Bt=XWtT): out = acc + bt[col] + Qb[row][col]  (fp32)
template<int MODE>
__global__ __launch_bounds__(256) void gemm_mfma(
    const ushort* __restrict__ A,
    const ushort* __restrict__ Bt0, const ushort* __restrict__ Bt1,
    const ushort* __restrict__ Bt2,
    const float* __restrict__ bq, const float* __restrict__ bk,
    float* __restrict__ Qb, float* __restrict__ Eq,
    float* __restrict__ EkT, ushort* __restrict__ XWtT,
    const float* __restrict__ bt, const float* __restrict__ addend,
    float* __restrict__ out, int K)
{
    const int N = D;
    const int bz = (MODE == 0) ? blockIdx.z : 0;
    const ushort* Bt = (MODE == 1) ? Bt0 : (bz == 0 ? Bt0 : bz == 1 ? Bt1 : Bt2);

    __shared__ ushort As[32][72];   // +8 pad
    __shared__ ushort Bs[64][72];

    const int m0 = blockIdx.y * 32;
    const int n0 = blockIdx.x * 64;
    const int t = threadIdx.x;
    const int l = t & 63, w = t >> 6;
    const int wr = w >> 1, wc = w & 1;
    const int frow = l & 15;
    const int kg = (l >> 4) * 8;

    const int srow = t >> 3;         // 0..31
    const int sk   = (t & 7) * 8;    // 0..56

    f32x4 acc[2] = {};

    for (int k0 = 0; k0 < K; k0 += 64) {
        uint4 a0 = *(const uint4*)&A [(m0 + srow)      * K + k0 + sk];
        uint4 b0 = *(const uint4*)&Bt[(n0 + srow)      * K + k0 + sk];
        uint4 b1 = *(const uint4*)&Bt[(n0 + srow + 32) * K + k0 + sk];
        if (k0) __syncthreads();
        *(uint4*)&As[srow][sk]      = a0;
        *(uint4*)&Bs[srow][sk]      = b0;
        *(uint4*)&Bs[srow + 32][sk] = b1;
        __syncthreads();

        bf16x8 af[2], bfr[2][2];
        #pragma unroll
        for (int kk = 0; kk < 2; ++kk) {
            af[kk] = *(const bf16x8*)&As[16 * wr + frow][32 * kk + kg];
            #pragma unroll
            for (int fc = 0; fc < 2; ++fc)
                bfr[fc][kk] = *(const bf16x8*)&Bs[32 * wc + 16 * fc + frow][32 * kk + kg];
        }
        #pragma unroll
        for (int fc = 0; fc < 2; ++fc) {
            acc[fc] = __builtin_amdgcn_mfma_f32_16x16x32_bf16(af[0], bfr[fc][0], acc[fc], 0, 0, 0);
            acc[fc] = __builtin_amdgcn_mfma_f32_16x16x32_bf16(af[1], bfr[fc][1], acc[fc], 0, 0, 0);
        }
    }

    const int rg = (l >> 4) * 4;
    #pragma unroll
    for (int fc = 0; fc < 2; ++fc) {
        const int col = n0 + 32 * wc + 16 * fc + frow;
        const int row0 = m0 + 16 * wr + rg;       // multiple of 4
        if (MODE == 0 && bz == 2) {
            ushort4 e;
            e.x = f2bf(acc[fc][0]);
            e.y = f2bf(acc[fc][1]);
            e.z = f2bf(acc[fc][2]);
            e.w = f2bf(acc[fc][3]);
            *(ushort4*)&XWtT[col * L + row0] = e;
        } else if (MODE == 0 && bz == 1) {
            const float bv = bk[col];
            float4 e;
            e.x = __builtin_amdgcn_exp2f(LOG2E2 * (acc[fc][0] + bv));
            e.y = __builtin_amdgcn_exp2f(LOG2E2 * (acc[fc][1] + bv));
            e.z = __builtin_amdgcn_exp2f(LOG2E2 * (acc[fc][2] + bv));
            e.w = __builtin_amdgcn_exp2f(LOG2E2 * (acc[fc][3] + bv));
            *(float4*)&EkT[col * L + row0] = e;
        } else if (MODE == 0) {
            const float bv = bq[col];
            #pragma unroll
            for (int i = 0; i < 4; ++i) {
                float v = acc[fc][i] + bv;
                Qb[(row0 + i) * N + col] = v;
                Eq[(row0 + i) * N + col] = __builtin_amdgcn_exp2f(LOG2E2 * v);
            }
        } else {
            const float bv = bt[col];
            #pragma unroll
            for (int i = 0; i < 4; ++i)
                out[(row0 + i) * N + col] =
                    acc[fc][i] + bv + addend[(row0 + i) * N + col];
        }
    }
}

// ---------------- partial scores: lane = k, LDS-broadcast Eq ------------------
// Grid (2 kt, 16 dh, 64 qg) x 256 threads (4 waves) = 2048 blocks = 8192 waves
// -> 100% occupancy cap (launch_bounds pins VGPR <= 64). Block stages 8 q-rows
// of Eq (d-range 48) plus -2*w into LDS (uniform-addr broadcast reads). Lane
// owns k; 8 independent rcp chains; zero cross-lane ops.
// partial[dh][q][k] = sum_d (-2 w_d)*rcp(eq*ek+1); mask added in softmax.
__global__ __launch_bounds__(256, 8) void score_k(
    const float* __restrict__ Eq, const float* __restrict__ EkT,
    const float* __restrict__ w_att, float* __restrict__ sP)
{
    __shared__ float eqlds[DSEG][12];   // {eq q0..q7, -2w, pad x3} per d
    const int kt = blockIdx.x;          // 0..1
    const int dh = blockIdx.y;          // 0..15
    const int qg = blockIdx.z;          // 0..63
    const int q0 = qg * QB;
    const int dbase = dh * DSEG;
    const int tid = threadIdx.x;
    const int lane = tid & 63, wv = tid >> 6;
    const int k = kt * 256 + wv * 64 + lane;

    // stage: 8 rows x 48 cols = 384 elements over 256 threads
    for (int idx = tid; idx < QB * DSEG; idx += 256) {
        int row = idx / DSEG;
        int d   = idx - row * DSEG;
        eqlds[d][row] = Eq[(q0 + row) * D + dbase + d];
    }
    if (tid < DSEG) eqlds[tid][8] = -2.f * w_att[dbase + tid];
    __syncthreads();

    const float* __restrict__ ekp = EkT + dbase * L + k;
    float acc[QB] = {};
    #pragma unroll 4
    for (int d = 0; d < DSEG; ++d) {
        float ek = ekp[d * L];
        float4 eA = *(const float4*)&eqlds[d][0];
        float4 eB = *(const float4*)&eqlds[d][4];
        float wd = eqlds[d][8];
        acc[0] = fmaf(wd, __builtin_amdgcn_rcpf(fmaf(eA.x, ek, 1.f)), acc[0]);
        acc[1] = fmaf(wd, __builtin_amdgcn_rcpf(fmaf(eA.y, ek, 1.f)), acc[1]);
        acc[2] = fmaf(wd, __builtin_amdgcn_rcpf(fmaf(eA.z, ek, 1.f)), acc[2]);
        acc[3] = fmaf(wd, __builtin_amdgcn_rcpf(fmaf(eA.w, ek, 1.f)), acc[3]);
        acc[4] = fmaf(wd, __builtin_amdgcn_rcpf(fmaf(eB.x, ek, 1.f)), acc[4]);
        acc[5] = fmaf(wd, __builtin_amdgcn_rcpf(fmaf(eB.y, ek, 1.f)), acc[5]);
        acc[6] = fmaf(wd, __builtin_amdgcn_rcpf(fmaf(eB.z, ek, 1.f)), acc[6]);
        acc[7] = fmaf(wd, __builtin_amdgcn_rcpf(fmaf(eB.w, ek, 1.f)), acc[7]);
    }

    float* __restrict__ dst = sP + dh * LL + q0 * L + k;
    #pragma unroll
    for (int q = 0; q < QB; ++q)
        dst[q * L] = acc[q];
}

// ---------------- softmax (sum of 16 d-partials + mask) -> bf16 probs ---------
__global__ __launch_bounds__(512) void softmax_probs(
    const float* __restrict__ sP, const float* __restrict__ mask,
    ushort* __restrict__ Pbf)
{
    __shared__ float redA[8], redB[8], redC[8], redD[8];
    const int q0 = blockIdx.x * 2;
    const int tid = threadIdx.x;
    const int lane = tid & 63, wave = tid >> 6;

    float v0 = mask[tid], v1 = v0;
    #pragma unroll
    for (int h = 0; h < DH; ++h) {
        v0 += sP[h * LL + q0 * L + tid];
        v1 += sP[h * LL + (q0 + 1) * L + tid];
    }

    float m0 = v0, m1 = v1;
    #pragma unroll
    for (int off = 32; off; off >>= 1) {
        m0 = fmaxf(m0, __shfl_xor(m0, off));
        m1 = fmaxf(m1, __shfl_xor(m1, off));
    }
    if (lane == 0) { redA[wave] = m0; redB[wave] = m1; }
    __syncthreads();
    float mm0 = redA[0], mm1 = redB[0];
    #pragma unroll
    for (int i = 1; i < 8; ++i) { mm0 = fmaxf(mm0, redA[i]); mm1 = fmaxf(mm1, redB[i]); }
    float e0 = __builtin_amdgcn_exp2f(LOG2E * (v0 - mm0));
    float e1 = __builtin_amdgcn_exp2f(LOG2E * (v1 - mm1));
    float s0 = e0, s1 = e1;
    #pragma unroll
    for (int off = 32; off; off >>= 1) {
        s0 += __shfl_xor(s0, off);
        s1 += __shfl_xor(s1, off);
    }
    if (lane == 0) { redC[wave] = s0; redD[wave] = s1; }
    __syncthreads();
    float t0 = redC[0], t1 = redD[0];
    #pragma unroll
    for (int i = 1; i < 8; ++i) { t0 += redC[i]; t1 += redD[i]; }
    Pbf[q0 * L + tid]       = f2bf(e0 * __builtin_amdgcn_rcpf(t0));
    Pbf[(q0 + 1) * L + tid] = f2bf(e1 * __builtin_amdgcn_rcpf(t1));
}

extern "C" void kernel_launch(void* const* d_in, const int* in_sizes, int n_in,
                              void* d_out, int out_size, void* d_ws, size_t ws_size,
                              hipStream_t stream) {
    const float* X     = (const float*)d_in[0];
    const float* mask  = (const float*)d_in[1];
    const float* Wq    = (const float*)d_in[2];
    const float* bq    = (const float*)d_in[3];
    const float* Wk    = (const float*)d_in[4];
    const float* bk    = (const float*)d_in[5];
    const float* w_att = (const float*)d_in[6];
    // d_in[7] = b_att: row-constant -> softmax-invariant; dropped.
    const float* Wt    = (const float*)d_in[8];
    const float* bt    = (const float*)d_in[9];
    float* out = (float*)d_out;

    const int LD = L * D, DD = D * D;
    float*  Qb   = (float*)d_ws;          // [L*D] fp32 Q (final addend)
    float*  Eq   = Qb + LD;               // [L*D] exp2(c*Q) row-major
    float*  EkT  = Eq + LD;               // [D][L] exp2(c*K) transposed
    float*  sP   = EkT + LD;              // [DH][L][L] partial scores
    ushort* Xbf  = (ushort*)(sP + DH * LL); // [L*D] bf16 X
    ushort* WqT  = Xbf + LD;              // [D][D]
    ushort* WkT  = WqT + DD;
    ushort* WtT  = WkT + DD;
    ushort* XWtT = WtT + DD;              // [D][L] bf16 (X@Wt)^T
    ushort* Pbf  = XWtT + LD;             // [L][L] bf16 probs

    // prep: bf16 cast of X + transposes of Wq/Wk/Wt
    transpose_cast<<<dim3(D / 64, D / 64, 4), 256, 0, stream>>>(
        X, Wq, Wk, Wt, Xbf, WqT, WkT, WtT);

    // z=0: Qb+Eq ; z=1: EkT ; z=2: XWtT    (one fused launch, K=768)
    gemm_mfma<0><<<dim3(D / 64, L / 32, 3), 256, 0, stream>>>(
        Xbf, WqT, WkT, WtT, bq, bk, Qb, Eq, EkT, XWtT, nullptr, nullptr, nullptr, D);

    // partial scores: lane = k, LDS-broadcast Eq, 100%-occupancy grid
    score_k<<<dim3(2, DH, L / QB), 256, 0, stream>>>(Eq, EkT, w_att, sP);

    // softmax over the 16 partials (+mask) -> bf16 probs
    softmax_probs<<<dim3(L / 2), 512, 0, stream>>>(sP, mask, Pbf);

    // out = P @ XWt + bt + Q   (K=512)
    gemm_mfma<1><<<dim3(D / 64, L / 32, 1), 256, 0, stream>>>(
        Pbf, XWtT, nullptr, nullptr, nullptr, nullptr, nullptr, nullptr, nullptr,
        nullptr, bt, Qb, out, L);
}

// Round 15
// 52.606 us; speedup vs baseline: 1.0610x; 1.0610x over previous
//
#include <hip/hip_runtime.h>

#define L 512
#define D 768
#define LL (L * L)
#define LOG2E  1.44269504088896341f
#define LOG2E2 2.88539008177792681f   // 2*log2(e)
#define DH 8                           // d-split factor (r13 config; 16 regressed)
#define DSEG (D / DH)                  // 96
#define QB 8                           // q-rows per block in score_k

typedef __attribute__((ext_vector_type(8))) short bf16x8;
typedef __attribute__((ext_vector_type(4))) float f32x4;

__device__ __forceinline__ ushort f2bf(float f) {
    unsigned u = __builtin_bit_cast(unsigned, f);
    u += 0x7FFFu + ((u >> 16) & 1u);          // RNE
    return (ushort)(u >> 16);
}

// ---------------- prep: cast X->bf16; transposed bf16 copies of Wq/Wk/Wt ------
// z: 0 = X cast only (512x768), 1 = Wq^T, 2 = Wk^T, 3 = Wt^T (768x768)
__global__ __launch_bounds__(256) void transpose_cast(
    const float* __restrict__ X,  const float* __restrict__ Wq,
    const float* __restrict__ Wk, const float* __restrict__ Wt,
    ushort* __restrict__ Xbf,
    ushort* __restrict__ WqT, ushort* __restrict__ WkT, ushort* __restrict__ WtT)
{
    __shared__ float tile[64][65];
    const int z = blockIdx.z;
    const float* src = z == 0 ? X : z == 1 ? Wq : z == 2 ? Wk : Wt;
    ushort* dstT     = z == 1 ? WqT : z == 2 ? WkT : WtT;
    const int R = (z == 0) ? L : D;
    const int r0 = blockIdx.y * 64, c0 = blockIdx.x * 64;
    if (r0 >= R) return;
    const int t = threadIdx.x;
    const int tr = t >> 4;           // 0..15
    const int tc = (t & 15) * 4;     // 0..60
    #pragma unroll
    for (int p = 0; p < 4; ++p) {
        int r = tr + p * 16;
        float4 v = *(const float4*)&src[(r0 + r) * D + c0 + tc];
        tile[r][tc + 0] = v.x; tile[r][tc + 1] = v.y;
        tile[r][tc + 2] = v.z; tile[r][tc + 3] = v.w;
        if (z == 0) {
            ushort4 b;
            b.x = f2bf(v.x); b.y = f2bf(v.y); b.z = f2bf(v.z); b.w = f2bf(v.w);
            *(ushort4*)&Xbf[(r0 + r) * D + c0 + tc] = b;
        }
    }
    if (z == 0) return;
    __syncthreads();
    #pragma unroll
    for (int p = 0; p < 4; ++p) {
        int c = tr + p * 16;
        ushort4 b;
        b.x = f2bf(tile[tc + 0][c]);
        b.y = f2bf(tile[tc + 1][c]);
        b.z = f2bf(tile[tc + 2][c]);
        b.w = f2bf(tile[tc + 3][c]);
        *(ushort4*)&dstT[(c0 + c) * R + r0 + tc] = b;
    }
}

// ---------------- bf16 MFMA GEMM, 32x64 tile, BK=64, 4 waves ------------------
// Software-pipelined staging: iteration k+1's global loads are issued right
// after the barrier, so L2 latency hides under the MFMA compute of iteration k.
// MODE 0 (z in {0,1,2}, K=768, A=Xbf):
//   z=0: Qb = acc + bq (fp32) AND Eq = exp2(c*(acc+bq)) (fp32), both row-major
//   z=1: EkT[col][row0..3] = exp2(c*(acc + bk))   (transposed float4 store)
//   z=2: XWtT[col][row0..3] = bf16(acc)           (transposed ushort4 store)
// MODE 1 (K=512, A=Pbf, Bt=XWtT): out = acc + bt[col] + Qb[row][col]  (fp32)
template<int MODE>
__global__ __launch_bounds__(256) void gemm_mfma(
    const ushort* __restrict__ A,
    const ushort* __restrict__ Bt0, const ushort* __restrict__ Bt1,
    const ushort* __restrict__ Bt2,
    const float* __restrict__ bq, const float* __restrict__ bk,
    float* __restrict__ Qb, float* __restrict__ Eq,
    float* __restrict__ EkT, ushort* __restrict__ XWtT,
    const float* __restrict__ bt, const float* __restrict__ addend,
    float* __restrict__ out, int K)
{
    const int N = D;
    const int bz = (MODE == 0) ? blockIdx.z : 0;
    const ushort* Bt = (MODE == 1) ? Bt0 : (bz == 0 ? Bt0 : bz == 1 ? Bt1 : Bt2);

    __shared__ ushort As[32][72];   // +8 pad
    __shared__ ushort Bs[64][72];

    const int m0 = blockIdx.y * 32;
    const int n0 = blockIdx.x * 64;
    const int t = threadIdx.x;
    const int l = t & 63, w = t >> 6;
    const int wr = w >> 1, wc = w & 1;
    const int frow = l & 15;
    const int kg = (l >> 4) * 8;

    const int srow = t >> 3;         // 0..31
    const int sk   = (t & 7) * 8;    // 0..56

    const ushort* Ap  = A  + (m0 + srow) * K + sk;
    const ushort* Bp0 = Bt + (n0 + srow) * K + sk;
    const ushort* Bp1 = Bt + (n0 + srow + 32) * K + sk;

    uint4 a0 = *(const uint4*)Ap;
    uint4 b0 = *(const uint4*)Bp0;
    uint4 b1 = *(const uint4*)Bp1;

    f32x4 acc[2] = {};

    for (int k0 = 0; k0 < K; k0 += 64) {
        if (k0) __syncthreads();
        *(uint4*)&As[srow][sk]      = a0;
        *(uint4*)&Bs[srow][sk]      = b0;
        *(uint4*)&Bs[srow + 32][sk] = b1;
        __syncthreads();
        if (k0 + 64 < K) {                      // prefetch next tile under MFMA
            a0 = *(const uint4*)(Ap  + k0 + 64);
            b0 = *(const uint4*)(Bp0 + k0 + 64);
            b1 = *(const uint4*)(Bp1 + k0 + 64);
        }

        bf16x8 af[2], bfr[2][2];
        #pragma unroll
        for (int kk = 0; kk < 2; ++kk) {
            af[kk] = *(const bf16x8*)&As[16 * wr + frow][32 * kk + kg];
            #pragma unroll
            for (int fc = 0; fc < 2; ++fc)
                bfr[fc][kk] = *(const bf16x8*)&Bs[32 * wc + 16 * fc + frow][32 * kk + kg];
        }
        #pragma unroll
        for (int fc = 0; fc < 2; ++fc) {
            acc[fc] = __builtin_amdgcn_mfma_f32_16x16x32_bf16(af[0], bfr[fc][0], acc[fc], 0, 0, 0);
            acc[fc] = __builtin_amdgcn_mfma_f32_16x16x32_bf16(af[1], bfr[fc][1], acc[fc], 0, 0, 0);
        }
    }

    const int rg = (l >> 4) * 4;
    #pragma unroll
    for (int fc = 0; fc < 2; ++fc) {
        const int col = n0 + 32 * wc + 16 * fc + frow;
        const int row0 = m0 + 16 * wr + rg;       // multiple of 4
        if (MODE == 0 && bz == 2) {
            ushort4 e;
            e.x = f2bf(acc[fc][0]);
            e.y = f2bf(acc[fc][1]);
            e.z = f2bf(acc[fc][2]);
            e.w = f2bf(acc[fc][3]);
            *(ushort4*)&XWtT[col * L + row0] = e;
        } else if (MODE == 0 && bz == 1) {
            const float bv = bk[col];
            float4 e;
            e.x = __builtin_amdgcn_exp2f(LOG2E2 * (acc[fc][0] + bv));
            e.y = __builtin_amdgcn_exp2f(LOG2E2 * (acc[fc][1] + bv));
            e.z = __builtin_amdgcn_exp2f(LOG2E2 * (acc[fc][2] + bv));
            e.w = __builtin_amdgcn_exp2f(LOG2E2 * (acc[fc][3] + bv));
            *(float4*)&EkT[col * L + row0] = e;
        } else if (MODE == 0) {
            const float bv = bq[col];
            #pragma unroll
            for (int i = 0; i < 4; ++i) {
                float v = acc[fc][i] + bv;
                Qb[(row0 + i) * N + col] = v;
                Eq[(row0 + i) * N + col] = __builtin_amdgcn_exp2f(LOG2E2 * v);
            }
        } else {
            const float bv = bt[col];
            #pragma unroll
            for (int i = 0; i < 4; ++i)
                out[(row0 + i) * N + col] =
                    acc[fc][i] + bv + addend[(row0 + i) * N + col];
        }
    }
}

// ---------------- partial scores: lane = k, LDS-broadcast Eq (r13 config) -----
// Grid (2 kt, 8 dh, 64 qg) x 256 threads (4 waves). Block stages 8 q-rows of Eq
// (d-range 96) plus -2*w into LDS (uniform-addr broadcast reads). Lane owns k;
// 8 independent rcp chains; zero cross-lane ops.
// partial[dh][q][k] = sum_d (-2 w_d)*rcp(eq*ek+1); mask added in softmax.
__global__ __launch_bounds__(256) void score_k(
    const float* __restrict__ Eq, const float* __restrict__ EkT,
    const float* __restrict__ w_att, float* __restrict__ sP)
{
    __shared__ float eqlds[DSEG][12];   // {eq q0..q7, -2w, pad x3} per d
    const int kt = blockIdx.x;          // 0..1
    const int dh = blockIdx.y;          // 0..7
    const int qg = blockIdx.z;          // 0..63
    const int q0 = qg * QB;
    const int dbase = dh * DSEG;
    const int tid = threadIdx.x;
    const int lane = tid & 63, wv = tid >> 6;
    const int k = kt * 256 + wv * 64 + lane;

    {   // stage: 8 rows x 96 cols, 32 threads per row, 3 cols each
        const int row = tid >> 5;       // 0..7
        const int j   = tid & 31;
        #pragma unroll
        for (int c = 0; c < 3; ++c) {
            int d = j + 32 * c;
            eqlds[d][row] = Eq[(q0 + row) * D + dbase + d];
        }
        if (tid < 32) {
            #pragma unroll
            for (int c = 0; c < 3; ++c) {
                int d = tid + 32 * c;
                eqlds[d][8] = -2.f * w_att[dbase + d];
            }
        }
    }
    __syncthreads();

    const float* __restrict__ ekp = EkT + dbase * L + k;
    float acc[QB] = {};
    #pragma unroll 4
    for (int d = 0; d < DSEG; ++d) {
        float ek = ekp[d * L];
        float4 eA = *(const float4*)&eqlds[d][0];
        float4 eB = *(const float4*)&eqlds[d][4];
        float wd = eqlds[d][8];
        acc[0] = fmaf(wd, __builtin_amdgcn_rcpf(fmaf(eA.x, ek, 1.f)), acc[0]);
        acc[1] = fmaf(wd, __builtin_amdgcn_rcpf(fmaf(eA.y, ek, 1.f)), acc[1]);
        acc[2] = fmaf(wd, __builtin_amdgcn_rcpf(fmaf(eA.z, ek, 1.f)), acc[2]);
        acc[3] = fmaf(wd, __builtin_amdgcn_rcpf(fmaf(eA.w, ek, 1.f)), acc[3]);
        acc[4] = fmaf(wd, __builtin_amdgcn_rcpf(fmaf(eB.x, ek, 1.f)), acc[4]);
        acc[5] = fmaf(wd, __builtin_amdgcn_rcpf(fmaf(eB.y, ek, 1.f)), acc[5]);
        acc[6] = fmaf(wd, __builtin_amdgcn_rcpf(fmaf(eB.z, ek, 1.f)), acc[6]);
        acc[7] = fmaf(wd, __builtin_amdgcn_rcpf(fmaf(eB.w, ek, 1.f)), acc[7]);
    }

    float* __restrict__ dst = sP + dh * LL + q0 * L + k;
    #pragma unroll
    for (int q = 0; q < QB; ++q)
        dst[q * L] = acc[q];
}

// ---------------- softmax (sum of 8 d-partials + mask) -> bf16 probs ----------
__global__ __launch_bounds__(512) void softmax_probs(
    const float* __restrict__ sP, const float* __restrict__ mask,
    ushort* __restrict__ Pbf)
{
    __shared__ float redA[8], redB[8], redC[8], redD[8];
    const int q0 = blockIdx.x * 2;
    const int tid = threadIdx.x;
    const int lane = tid & 63, wave = tid >> 6;

    float v0 = mask[tid], v1 = v0;
    #pragma unroll
    for (int h = 0; h < DH; ++h) {
        v0 += sP[h * LL + q0 * L + tid];
        v1 += sP[h * LL + (q0 + 1) * L + tid];
    }

    float m0 = v0, m1 = v1;
    #pragma unroll
    for (int off = 32; off; off >>= 1) {
        m0 = fmaxf(m0, __shfl_xor(m0, off));
        m1 = fmaxf(m1, __shfl_xor(m1, off));
    }
    if (lane == 0) { redA[wave] = m0; redB[wave] = m1; }
    __syncthreads();
    float mm0 = redA[0], mm1 = redB[0];
    #pragma unroll
    for (int i = 1; i < 8; ++i) { mm0 = fmaxf(mm0, redA[i]); mm1 = fmaxf(mm1, redB[i]); }
    float e0 = __builtin_amdgcn_exp2f(LOG2E * (v0 - mm0));
    float e1 = __builtin_amdgcn_exp2f(LOG2E * (v1 - mm1));
    float s0 = e0, s1 = e1;
    #pragma unroll
    for (int off = 32; off; off >>= 1) {
        s0 += __shfl_xor(s0, off);
        s1 += __shfl_xor(s1, off);
    }
    if (lane == 0) { redC[wave] = s0; redD[wave] = s1; }
    __syncthreads();
    float t0 = redC[0], t1 = redD[0];
    #pragma unroll
    for (int i = 1; i < 8; ++i) { t0 += redC[i]; t1 += redD[i]; }
    Pbf[q0 * L + tid]       = f2bf(e0 * __builtin_amdgcn_rcpf(t0));
    Pbf[(q0 + 1) * L + tid] = f2bf(e1 * __builtin_amdgcn_rcpf(t1));
}

extern "C" void kernel_launch(void* const* d_in, const int* in_sizes, int n_in,
                              void* d_out, int out_size, void* d_ws, size_t ws_size,
                              hipStream_t stream) {
    const float* X     = (const float*)d_in[0];
    const float* mask  = (const float*)d_in[1];
    const float* Wq    = (const float*)d_in[2];
    const float* bq    = (const float*)d_in[3];
    const float* Wk    = (const float*)d_in[4];
    const float* bk    = (const float*)d_in[5];
    const float* w_att = (const float*)d_in[6];
    // d_in[7] = b_att: row-constant -> softmax-invariant; dropped.
    const float* Wt    = (const float*)d_in[8];
    const float* bt    = (const float*)d_in[9];
    float* out = (float*)d_out;

    const int LD = L * D, DD = D * D;
    float*  Qb   = (float*)d_ws;          // [L*D] fp32 Q (final addend)
    float*  Eq   = Qb + LD;               // [L*D] exp2(c*Q) row-major
    float*  EkT  = Eq + LD;               // [D][L] exp2(c*K) transposed
    float*  sP   = EkT + LD;              // [DH][L][L] partial scores
    ushort* Xbf  = (ushort*)(sP + DH * LL); // [L*D] bf16 X
    ushort* WqT  = Xbf + LD;              // [D][D]
    ushort* WkT  = WqT + DD;
    ushort* WtT  = WkT + DD;
    ushort* XWtT = WtT + DD;              // [D][L] bf16 (X@Wt)^T
    ushort* Pbf  = XWtT + LD;             // [L][L] bf16 probs

    // prep: bf16 cast of X + transposes of Wq/Wk/Wt
    transpose_cast<<<dim3(D / 64, D / 64, 4), 256, 0, stream>>>(
        X, Wq, Wk, Wt, Xbf, WqT, WkT, WtT);

    // z=0: Qb+Eq ; z=1: EkT ; z=2: XWtT    (one fused launch, K=768, pipelined)
    gemm_mfma<0><<<dim3(D / 64, L / 32, 3), 256, 0, stream>>>(
        Xbf, WqT, WkT, WtT, bq, bk, Qb, Eq, EkT, XWtT, nullptr, nullptr, nullptr, D);

    // partial scores: lane = k, LDS-broadcast Eq
    score_k<<<dim3(2, DH, L / QB), 256, 0, stream>>>(Eq, EkT, w_att, sP);

    // softmax over the 8 partials (+mask) -> bf16 probs
    softmax_probs<<<dim3(L / 2), 512, 0, stream>>>(sP, mask, Pbf);

    // out = P @ XWt + bt + Q   (K=512, pipelined)
    gemm_mfma<1><<<dim3(D / 64, L / 32, 1), 256, 0, stream>>>(
        Pbf, XWtT, nullptr, nullptr, nullptr, nullptr, nullptr, nullptr, nullptr,
        nullptr, bt, Qb, out, L);
}